// Round 1
// baseline (340.184 us; speedup 1.0000x reference)
//
#include <hip/hip_runtime.h>

// AttentionGate: out[b,cf,v] = x[b,cf,v] * sigmoid(Wpsi · relu(Wg·g[b,:,v] + Wx·x[b,:,v]))
// Shapes: B=2, CF=CG=64, CI=32, spatial S=64^3=262144. All fp32.
//
// Strategy: 1 thread per voxel, lanes over consecutive voxels (coalesced 256B/instr).
// Weights pre-transposed+concatenated into Wcat[c][64] (WgT | WxT) so the inner loop
// reads contiguous wave-uniform weights -> s_load_dwordx16 into SGPRs (scalar pipe).
// 32 independent accumulators (ILP). x re-read in the epilogue (L1/L2-warm, no HBM cost).

#define SPAT 262144        // 64*64*64 voxels per (b, channel) plane
#define NVOX 524288        // B * SPAT
#define CIN  64            // CF == CG
#define COUT 32            // CI

__global__ __launch_bounds__(256) void transpose_w(const float* __restrict__ Wg,
                                                   const float* __restrict__ Wx,
                                                   float* __restrict__ Wcat) {
    int idx = blockIdx.x * 256 + threadIdx.x;   // 0..4095
    int c = idx >> 6;        // input channel 0..63
    int o = idx & 63;        // 0..31 -> Wg row, 32..63 -> Wx row
    float v = (o < 32) ? Wg[o * CIN + c] : Wx[(o - 32) * CIN + c];
    Wcat[c * 64 + o] = v;
}

__global__ __launch_bounds__(256) void gate_main(const float* __restrict__ x,
                                                 const float* __restrict__ g,
                                                 const float* __restrict__ Wcat,
                                                 const float* __restrict__ Wpsi,
                                                 float* __restrict__ out) {
    int v = blockIdx.x * 256 + threadIdx.x;     // 0..NVOX-1
    int b = v >> 18;                            // batch (SPAT = 2^18)
    int s = v & (SPAT - 1);                     // spatial index

    const float* __restrict__ xp = x + (size_t)b * CIN * SPAT + s;
    const float* __restrict__ gp = g + (size_t)b * CIN * SPAT + s;

    float acc[COUT];
#pragma unroll
    for (int o = 0; o < COUT; ++o) acc[o] = 0.0f;

#pragma unroll 4
    for (int c = 0; c < CIN; ++c) {
        float gc = gp[(size_t)c * SPAT];
        float xc = xp[(size_t)c * SPAT];
        const float* w = Wcat + c * 64;         // wave-uniform address -> s_load
#pragma unroll
        for (int o = 0; o < COUT; ++o)
            acc[o] = fmaf(w[o], gc, fmaf(w[32 + o], xc, acc[o]));
    }

    float p = 0.0f;
#pragma unroll
    for (int o = 0; o < COUT; ++o)
        p = fmaf(Wpsi[o], fmaxf(acc[o], 0.0f), p);

    float psi = 1.0f / (1.0f + __expf(-p));

    float* __restrict__ op = out + (size_t)b * CIN * SPAT + s;
#pragma unroll 4
    for (int c = 0; c < CIN; ++c)
        op[(size_t)c * SPAT] = xp[(size_t)c * SPAT] * psi;   // x re-read: L1/L2-warm
}

extern "C" void kernel_launch(void* const* d_in, const int* in_sizes, int n_in,
                              void* d_out, int out_size, void* d_ws, size_t ws_size,
                              hipStream_t stream) {
    const float* x    = (const float*)d_in[0];
    const float* g    = (const float*)d_in[1];
    const float* Wg   = (const float*)d_in[2];
    const float* Wx   = (const float*)d_in[3];
    const float* Wpsi = (const float*)d_in[4];
    float* out  = (float*)d_out;
    float* Wcat = (float*)d_ws;                 // 64*64 floats = 16 KB scratch

    transpose_w<<<16, 256, 0, stream>>>(Wg, Wx, Wcat);
    gate_main<<<NVOX / 256, 256, 0, stream>>>(x, g, Wcat, Wpsi, out);
}

// Round 3
// 320.815 us; speedup vs baseline: 1.0604x; 1.0604x over previous
//
#include <hip/hip_runtime.h>

// AttentionGate: out[b,cf,v] = x[b,cf,v] * sigmoid(Wpsi · relu(Wg·g[b,:,v] + Wx·x[b,:,v]))
// B=2, CF=CG=64, CI=32, SPAT=64^3. fp32.
//
// R2: same as R1 (2 voxels/thread) but with clang ext_vector_type instead of
// HIP float2 — __builtin_nontemporal_* requires native vector types, not the
// HIP_vector_type struct. Theory unchanged: amortize per-channel weight s_loads
// over 2x FMAs, 512B wave transactions, launch_bounds(256,4) caps VGPR at 128.
// g/out get nontemporal hints so x stays cache-resident for the epilogue re-read.

#define SPAT 262144        // 64*64*64
#define NVOX 524288        // B * SPAT
#define CIN  64
#define COUT 32
#define S2   (SPAT / 2)    // vec2 elements per (b,c) plane = 2^17

typedef float v2f __attribute__((ext_vector_type(2)));

__global__ __launch_bounds__(256) void transpose_w(const float* __restrict__ Wg,
                                                   const float* __restrict__ Wx,
                                                   float* __restrict__ Wcat) {
    int idx = blockIdx.x * 256 + threadIdx.x;   // 0..4095
    int c = idx >> 6;
    int o = idx & 63;
    float v = (o < 32) ? Wg[o * CIN + c] : Wx[(o - 32) * CIN + c];
    Wcat[c * 64 + o] = v;
}

__global__ __launch_bounds__(256, 4) void gate_main(const v2f* __restrict__ x,
                                                    const v2f* __restrict__ g,
                                                    const float* __restrict__ Wcat,
                                                    const float* __restrict__ Wpsi,
                                                    v2f* __restrict__ out) {
    int p = blockIdx.x * 256 + threadIdx.x;     // pair index 0..262143
    int b = p >> 17;                            // S2 = 2^17
    int s = p & (S2 - 1);

    const v2f* __restrict__ xp = x + (size_t)b * CIN * S2 + s;
    const v2f* __restrict__ gp = g + (size_t)b * CIN * S2 + s;

    v2f acc[COUT];
#pragma unroll
    for (int o = 0; o < COUT; ++o) acc[o] = (v2f)(0.0f);

#pragma unroll 2
    for (int c = 0; c < CIN; ++c) {
        v2f gc = __builtin_nontemporal_load(gp + (size_t)c * S2);  // g read once
        v2f xc = xp[(size_t)c * S2];                               // x re-read later
        const float* w = Wcat + c * 64;         // wave-uniform -> scalar loads
#pragma unroll
        for (int o = 0; o < COUT; ++o) {
            float wg = w[o], wx = w[32 + o];
            acc[o].x = fmaf(wg, gc.x, fmaf(wx, xc.x, acc[o].x));
            acc[o].y = fmaf(wg, gc.y, fmaf(wx, xc.y, acc[o].y));
        }
    }

    float px = 0.0f, py = 0.0f;
#pragma unroll
    for (int o = 0; o < COUT; ++o) {
        float wp = Wpsi[o];
        px = fmaf(wp, fmaxf(acc[o].x, 0.0f), px);
        py = fmaf(wp, fmaxf(acc[o].y, 0.0f), py);
    }
    float psix = 1.0f / (1.0f + __expf(-px));
    float psiy = 1.0f / (1.0f + __expf(-py));

    v2f* __restrict__ op = out + (size_t)b * CIN * S2 + s;
#pragma unroll 4
    for (int c = 0; c < CIN; ++c) {
        v2f xv = xp[(size_t)c * S2];            // L1/L2-warm re-read
        v2f ov; ov.x = xv.x * psix; ov.y = xv.y * psiy;
        __builtin_nontemporal_store(ov, op + (size_t)c * S2);  // write-once
    }
}

extern "C" void kernel_launch(void* const* d_in, const int* in_sizes, int n_in,
                              void* d_out, int out_size, void* d_ws, size_t ws_size,
                              hipStream_t stream) {
    const float* x    = (const float*)d_in[0];
    const float* g    = (const float*)d_in[1];
    const float* Wg   = (const float*)d_in[2];
    const float* Wx   = (const float*)d_in[3];
    const float* Wpsi = (const float*)d_in[4];
    float* out  = (float*)d_out;
    float* Wcat = (float*)d_ws;                 // 64*64 floats = 16 KB scratch

    transpose_w<<<16, 256, 0, stream>>>(Wg, Wx, Wcat);
    gate_main<<<NVOX / 2 / 256, 256, 0, stream>>>((const v2f*)x, (const v2f*)g,
                                                  Wcat, Wpsi, (v2f*)out);
}